// Round 11
// baseline (140.348 us; speedup 1.0000x reference)
//
#include <hip/hip_runtime.h>

#define B_DIM 4096
#define I_DIM 1024
#define O_DIM 1024
#define ON_DIM 4096      // O * N fan-in columns
#define TILE_HALFS 4096  // one 128(m) x 32(k) fp16 tile image = 8 KB
                         // image order: [kb8(4)][m(128)][j(8)] halfs

typedef _Float16 half8   __attribute__((ext_vector_type(8)));
typedef float    floatx16 __attribute__((ext_vector_type(16)));

// ---------------------------------------------------------------------------
// Prep 1: blocks [0,1024): per-row softmax stats (max, 1/sum), wave per row.
//         blocks [1024,2048): xt tile writer (fp32->fp16, tiled image).
// ---------------------------------------------------------------------------
__global__ __launch_bounds__(256)
void ltn_prep1(const float* __restrict__ logits, const float* __restrict__ x,
               float2* __restrict__ stats, _Float16* __restrict__ xt) {
  const int t = threadIdx.x;
  if (blockIdx.x < 1024) {
    const int lane = t & 63, wv = t >> 6;
    const int row = blockIdx.x * 4 + wv;
    const float4* src = (const float4*)(logits + (size_t)row * I_DIM);
    float4 v[4];
#pragma unroll
    for (int j = 0; j < 4; j++) v[j] = src[j * 64 + lane];
    float m = -1e30f;
#pragma unroll
    for (int j = 0; j < 4; j++)
      m = fmaxf(m, fmaxf(fmaxf(v[j].x, v[j].y), fmaxf(v[j].z, v[j].w)));
#pragma unroll
    for (int off = 1; off < 64; off <<= 1) m = fmaxf(m, __shfl_xor(m, off));
    float s = 0.0f;
#pragma unroll
    for (int j = 0; j < 4; j++) {
      s += __expf(v[j].x - m) + __expf(v[j].y - m)
         + __expf(v[j].z - m) + __expf(v[j].w - m);
    }
#pragma unroll
    for (int off = 1; off < 64; off <<= 1) s += __shfl_xor(s, off);
    if (lane == 0) stats[row] = make_float2(m, 1.0f / s);
  } else {
    const int bid = blockIdx.x - 1024;
    const int mb = bid >> 5, kt = bid & 31;
    const int nn = t >> 1, hf = t & 1;
    const int row = mb * 128 + nn;
    const float4* src = (const float4*)(x + (size_t)row * I_DIM + kt * 32 + hf * 16);
    const float4 a = src[0], b = src[1], c = src[2], d = src[3];
    half8 h0, h1;
    h0[0] = (_Float16)a.x; h0[1] = (_Float16)a.y; h0[2] = (_Float16)a.z; h0[3] = (_Float16)a.w;
    h0[4] = (_Float16)b.x; h0[5] = (_Float16)b.y; h0[6] = (_Float16)b.z; h0[7] = (_Float16)b.w;
    h1[0] = (_Float16)c.x; h1[1] = (_Float16)c.y; h1[2] = (_Float16)c.z; h1[3] = (_Float16)c.w;
    h1[4] = (_Float16)d.x; h1[5] = (_Float16)d.y; h1[6] = (_Float16)d.z; h1[7] = (_Float16)d.w;
    _Float16* base = xt + ((size_t)mb * 32 + kt) * TILE_HALFS + (hf * 2) * 1024 + nn * 8;
    *(half8*)base = h0;
    *(half8*)(base + 1024) = h1;
  }
}

// ---------------------------------------------------------------------------
// Prep 2: wt tile writer — softmax-normalize 128x32 logits block into the
// tiled fp16 image; fully coalesced reads and writes.
// ---------------------------------------------------------------------------
__global__ __launch_bounds__(256)
void ltn_prep2(const float* __restrict__ logits, const float2* __restrict__ stats,
               _Float16* __restrict__ wt) {
  const int t  = threadIdx.x;
  const int nn = t >> 1, hf = t & 1;
  const int nb = blockIdx.x >> 5, kb = blockIdx.x & 31;
  const int row = nb * 128 + nn;
  const float2 st = stats[row];
  const float4* src = (const float4*)(logits + (size_t)row * I_DIM + kb * 32 + hf * 16);
  const float4 a = src[0], b = src[1], c = src[2], d = src[3];
  half8 h0, h1;
  h0[0] = (_Float16)(__expf(a.x - st.x) * st.y);
  h0[1] = (_Float16)(__expf(a.y - st.x) * st.y);
  h0[2] = (_Float16)(__expf(a.z - st.x) * st.y);
  h0[3] = (_Float16)(__expf(a.w - st.x) * st.y);
  h0[4] = (_Float16)(__expf(b.x - st.x) * st.y);
  h0[5] = (_Float16)(__expf(b.y - st.x) * st.y);
  h0[6] = (_Float16)(__expf(b.z - st.x) * st.y);
  h0[7] = (_Float16)(__expf(b.w - st.x) * st.y);
  h1[0] = (_Float16)(__expf(c.x - st.x) * st.y);
  h1[1] = (_Float16)(__expf(c.y - st.x) * st.y);
  h1[2] = (_Float16)(__expf(c.z - st.x) * st.y);
  h1[3] = (_Float16)(__expf(c.w - st.x) * st.y);
  h1[4] = (_Float16)(__expf(d.x - st.x) * st.y);
  h1[5] = (_Float16)(__expf(d.y - st.x) * st.y);
  h1[6] = (_Float16)(__expf(d.z - st.x) * st.y);
  h1[7] = (_Float16)(__expf(d.w - st.x) * st.y);
  _Float16* base = wt + ((size_t)nb * 32 + kb) * TILE_HALFS + (hf * 2) * 1024 + nn * 8;
  *(half8*)base = h0;
  *(half8*)(base + 1024) = h1;
}

// ---------------------------------------------------------------------------
// GEMM + sigmoid + LUT. 128x128 block, 4 waves (2x2, each 64x64 as 2x2 of
// MFMA 32x32x16). A staged in LDS (8KB dbuf); B fragments loaded DIRECT from
// the tiled global image (2x512B contiguous segments per b128 — not R4's
// 64x16B scatter) with one-iter register prefetch. Rationale: LDS BW was the
// binding floor (R9 128KB/iter vs 85B/cyc); this drops LDS to 24KB/iter and
// moves B's 16KB to the parallel TCP/L2 pipe. 4 blocks/CU (m97 overlap
// regime): LDS 16KB, __launch_bounds__(256,4) caps 128 VGPR (acc=64).
// ---------------------------------------------------------------------------
__global__ __launch_bounds__(256, 4)
void ltn_gemm_lut(const _Float16* __restrict__ xt,   // tiles [.][TILE_HALFS]
                  const _Float16* __restrict__ wt,
                  const float* __restrict__ lut,     // [O][16]
                  float* __restrict__ out) {         // [B][O]
  __shared__ _Float16 As[2][4][128][8];   // [buf][kb8][m][j], 8 KB per buffer

  const int tid  = threadIdx.x;
  const int lane = tid & 63;
  const int wv   = tid >> 6;     // 0..3
  const int wr   = wv >> 1;      // row-wave 0..1 (64 rows)
  const int wc   = wv & 1;       // col-wave 0..1 (64 cols)
  const int mb   = blockIdx.x;   // 0..31
  const int nb   = blockIdx.y;   // 0..31
  const int l31  = lane & 31;
  const int lhi  = lane >> 5;    // k-half selector

  const _Float16* baseA = xt + (size_t)mb * 32 * TILE_HALFS;
  // B lane pointer for (s=0,tn=0): kb=lhi slab, col = wc*64 + l31
  const _Float16* pB = wt + (size_t)nb * 32 * TILE_HALFS
                     + lhi * 1024 + (wc * 64 + l31) * 8;

  floatx16 acc[2][2];
#pragma unroll
  for (int i = 0; i < 2; i++)
#pragma unroll
    for (int j = 0; j < 2; j++) acc[i][j] = (floatx16)0.0f;

  // A staging: 8 chunks of 1KB, 2 GLLs per wave
  auto stageA = [&](int buf, int kt) {
#pragma unroll
    for (int s = 0; s < 2; s++) {
      const int c = wv * 2 + s;
      const _Float16* g = baseA + (size_t)kt * TILE_HALFS + c * 512 + lane * 8;
      __builtin_amdgcn_global_load_lds(
          (const __attribute__((address_space(1))) void*)g,
          (__attribute__((address_space(3))) void*)((char*)&As[buf][0][0][0] + c * 1024),
          16, 0, 0);
    }
  };
  // B fragments for one kt: bf[s*2+tn], offsets {0,+256,+2048,+2304} halfs
  auto loadB = [&](int kt, half8* bf) {
    const half8* p = (const half8*)(pB + (size_t)kt * TILE_HALFS);
    bf[0] = p[0];          // s=0, tn=0
    bf[1] = p[32];         // s=0, tn=1  (+32 cols * 8 halfs = 256)
    bf[2] = p[256];        // s=1, tn=0  (+2 kb8 slabs = 2048)
    bf[3] = p[288];        // s=1, tn=1
  };

  half8 bfc[4], bfn[4];
  stageA(0, 0);
  loadB(0, bfc);
  int buf = 0;
  for (int kt = 0; kt < 32; kt++) {
    __syncthreads();                    // drains prev stage (full compute in flight)
    if (kt + 1 < 32) { stageA(buf ^ 1, kt + 1); loadB(kt + 1, bfn); }
#pragma unroll
    for (int s = 0; s < 2; s++) {       // two k16 steps
      const int kb = s * 2 + lhi;
      half8 af[2];
#pragma unroll
      for (int tm = 0; tm < 2; tm++) {
        const int rr = wr * 2 + tm;     // 32-row group 0..3
        af[tm] = *(const half8*)&As[buf][kb][rr * 32 + l31][0];
      }
#pragma unroll
      for (int tm = 0; tm < 2; tm++)
#pragma unroll
        for (int tn = 0; tn < 2; tn++)
          acc[tm][tn] = __builtin_amdgcn_mfma_f32_32x32x16_f16(
              af[tm], bfc[s * 2 + tn], acc[tm][tn], 0, 0, 0);
    }
#pragma unroll
    for (int q = 0; q < 4; q++) bfc[q] = bfn[q];
    buf ^= 1;
  }

  // ---- fused epilogue: sigmoid -> gather 4 fan-in values -> LUT contraction
  // C/D 32x32: col=lane&31, row=(reg&3)+8*(reg>>2)+4*(lane>>5). The 4 fan-in
  // values of one o live in 4 consecutive lanes.
#pragma unroll
  for (int tn = 0; tn < 2; tn++) {
    const int o = (nb * 128 + wc * 64 + tn * 32 + l31) >> 2;
    const float4* lt4 = (const float4*)(lut + (size_t)o * 16);
    const float4 L0 = lt4[0], L1 = lt4[1], L2 = lt4[2], L3 = lt4[3];
#pragma unroll
    for (int tm = 0; tm < 2; tm++) {
#pragma unroll
      for (int r = 0; r < 16; r++) {
        const float v  = acc[tm][tn][r];
        const float sv = 1.0f / (1.0f + __expf(-v));
        const float s1 = __shfl_down(sv, 1);
        const float s2 = __shfl_down(sv, 2);
        const float s3 = __shfl_down(sv, 3);
        if ((lane & 3) == 0) {
          const float s0 = sv;
          const float a0 = L0.x + (L2.x - L0.x) * s3;
          const float a1 = L0.y + (L2.y - L0.y) * s3;
          const float a2 = L0.z + (L2.z - L0.z) * s3;
          const float a3 = L0.w + (L2.w - L0.w) * s3;
          const float a4 = L1.x + (L3.x - L1.x) * s3;
          const float a5 = L1.y + (L3.y - L1.y) * s3;
          const float a6 = L1.z + (L3.z - L1.z) * s3;
          const float a7 = L1.w + (L3.w - L1.w) * s3;
          const float b0 = a0 + (a4 - a0) * s2;
          const float b1 = a1 + (a5 - a1) * s2;
          const float b2 = a2 + (a6 - a2) * s2;
          const float b3 = a3 + (a7 - a3) * s2;
          const float c0 = b0 + (b2 - b0) * s1;
          const float c1 = b1 + (b3 - b1) * s1;
          const float res = c0 + (c1 - c0) * s0;
          const int row = mb * 128 + wr * 64 + tm * 32
                        + (r & 3) + 8 * (r >> 2) + 4 * lhi;
          out[(size_t)row * O_DIM + o] = res;
        }
      }
    }
  }
}

// ---------------------------------------------------------------------------
extern "C" void kernel_launch(void* const* d_in, const int* in_sizes, int n_in,
                              void* d_out, int out_size, void* d_ws, size_t ws_size,
                              hipStream_t stream) {
  const float* x      = (const float*)d_in[0];  // (B, I)
  const float* logits = (const float*)d_in[1];  // (O, N, I)
  const float* lut    = (const float*)d_in[2];  // (O, 16)
  float* out          = (float*)d_out;          // (B, O)

  _Float16* wt = (_Float16*)d_ws;                                  // 8 MB tiled
  _Float16* xt = (_Float16*)d_ws + (size_t)ON_DIM * I_DIM;         // 8 MB tiled
  // stats scratch parked in d_out (32 KB); GEMM fully overwrites d_out later.
  float2* stats = (float2*)d_out;

  ltn_prep1<<<2048, 256, 0, stream>>>(logits, x, stats, xt);
  ltn_prep2<<<1024, 256, 0, stream>>>(logits, stats, wt);
  dim3 grid(32, 32);
  ltn_gemm_lut<<<grid, 256, 0, stream>>>(xt, wt, lut, out);
}

// Round 12
// 136.881 us; speedup vs baseline: 1.0253x; 1.0253x over previous
//
#include <hip/hip_runtime.h>

#define B_DIM 4096
#define I_DIM 1024
#define O_DIM 1024
#define ON_DIM 4096
// Sub-tile granule: 16 rows x 32 k fp16 = 512 halfs = 1 KB, layout
// [kb8(4)][m16(16)][j(8)].  Global image: [group][kt(32)][512], so one
// 16-row group's full-K image (16 x 1024) is 32 KB CONTIGUOUS — this is
// what lets prep write coalesced while GEMM stages 1KB-contiguous chunks.

typedef _Float16 half8   __attribute__((ext_vector_type(8)));
typedef _Float16 half4_t __attribute__((ext_vector_type(4)));
typedef float    floatx16 __attribute__((ext_vector_type(16)));

#define SLAB 136   // 128-half sub-slab + 8 pad (breaks LDS bank conflicts)

// ---------------------------------------------------------------------------
// Prep 1: blocks [0,1024): per-row softmax stats (max, 1/sum), wave per row.
//         blocks [1024,1280): xt tile writer — 16-row group per block:
//         row-coalesced reads, LDS transpose, contiguous 32KB write.
// ---------------------------------------------------------------------------
__global__ __launch_bounds__(256)
void ltn_prep1(const float* __restrict__ logits, const float* __restrict__ x,
               float2* __restrict__ stats, _Float16* __restrict__ xt) {
  __shared__ _Float16 lds[128 * SLAB];
  const int t = threadIdx.x;
  if (blockIdx.x < 1024) {
    const int lane = t & 63, wv = t >> 6;
    const int row = blockIdx.x * 4 + wv;
    const float4* src = (const float4*)(logits + (size_t)row * I_DIM);
    float4 v[4];
#pragma unroll
    for (int j = 0; j < 4; j++) v[j] = src[j * 64 + lane];
    float m = -1e30f;
#pragma unroll
    for (int j = 0; j < 4; j++)
      m = fmaxf(m, fmaxf(fmaxf(v[j].x, v[j].y), fmaxf(v[j].z, v[j].w)));
#pragma unroll
    for (int off = 1; off < 64; off <<= 1) m = fmaxf(m, __shfl_xor(m, off));
    float s = 0.0f;
#pragma unroll
    for (int j = 0; j < 4; j++) {
      s += __expf(v[j].x - m) + __expf(v[j].y - m)
         + __expf(v[j].z - m) + __expf(v[j].w - m);
    }
#pragma unroll
    for (int off = 1; off < 64; off <<= 1) s += __shfl_xor(s, off);
    if (lane == 0) stats[row] = make_float2(m, 1.0f / s);
  } else {
    const int g    = blockIdx.x - 1024;       // 16-row group of x
    const int slab = t >> 1;                  // (kt,kb8) slab = (4t)>>3
    const int jo   = (t & 1) * 4;
#pragma unroll
    for (int i = 0; i < 16; i++) {            // one full 4KB row per iter
      const float4 v = *(const float4*)(x + (size_t)(g * 16 + i) * I_DIM + t * 4);
      half4_t h;
      h[0] = (_Float16)v.x; h[1] = (_Float16)v.y;
      h[2] = (_Float16)v.z; h[3] = (_Float16)v.w;
      *(half4_t*)&lds[slab * SLAB + i * 8 + jo] = h;
    }
    __syncthreads();
    _Float16* dst = xt + (size_t)g * 16384;   // contiguous 32KB per group
#pragma unroll
    for (int s = 0; s < 8; s++) {
      const int h = s * 2048 + t * 8;
      *(half8*)(dst + h) = *(const half8*)&lds[(h >> 7) * SLAB + (h & 127)];
    }
  }
}

// ---------------------------------------------------------------------------
// Prep 2: wt tile writer — same 16-row-group transpose, with softmax
// normalization (needs stats from prep1, hence a separate launch).
// ---------------------------------------------------------------------------
__global__ __launch_bounds__(256)
void ltn_prep2(const float* __restrict__ logits, const float2* __restrict__ stats,
               _Float16* __restrict__ wt) {
  __shared__ _Float16 lds[128 * SLAB];
  const int t    = threadIdx.x;
  const int g    = blockIdx.x;                // 16-row group of ON rows
  const int slab = t >> 1;
  const int jo   = (t & 1) * 4;
#pragma unroll
  for (int i = 0; i < 16; i++) {
    const int row = g * 16 + i;
    const float2 st = stats[row];
    const float4 v = *(const float4*)(logits + (size_t)row * I_DIM + t * 4);
    half4_t h;
    h[0] = (_Float16)(__expf(v.x - st.x) * st.y);
    h[1] = (_Float16)(__expf(v.y - st.x) * st.y);
    h[2] = (_Float16)(__expf(v.z - st.x) * st.y);
    h[3] = (_Float16)(__expf(v.w - st.x) * st.y);
    *(half4_t*)&lds[slab * SLAB + i * 8 + jo] = h;
  }
  __syncthreads();
  _Float16* dst = wt + (size_t)g * 16384;
#pragma unroll
  for (int s = 0; s < 8; s++) {
    const int h = s * 2048 + t * 8;
    *(half8*)(dst + h) = *(const half8*)&lds[(h >> 7) * SLAB + (h & 127)];
  }
}

// ---------------------------------------------------------------------------
// GEMM + sigmoid + LUT — R11's structure unchanged (128x128 block, 4 waves
// 2x2, each 64x64 as 2x2 of MFMA 32x32x16; A staged in 8KB-dbuf LDS via
// 1KB-contiguous GLLs; B direct from global, 2x512B segments/instr, one-iter
// register prefetch). Only the addressing changed for the 16-row granule.
// ---------------------------------------------------------------------------
__global__ __launch_bounds__(256, 4)
void ltn_gemm_lut(const _Float16* __restrict__ xt,
                  const _Float16* __restrict__ wt,
                  const float* __restrict__ lut,     // [O][16]
                  float* __restrict__ out) {         // [B][O]
  __shared__ _Float16 As[2][8][512];   // [buf][rowblk16 c][subtile], 8KB/buf

  const int tid  = threadIdx.x;
  const int lane = tid & 63;
  const int wv   = tid >> 6;     // 0..3
  const int wr   = wv >> 1;      // row-wave 0..1 (64 rows)
  const int wc   = wv & 1;       // col-wave 0..1 (64 cols)
  const int mb   = blockIdx.x;   // 0..31
  const int nb   = blockIdx.y;   // 0..31
  const int l31  = lane & 31;
  const int lhi  = lane >> 5;    // k-half selector

  // B lane pointer for (s=0,tn=0): group nb*8 + wc*4 + (l31>>4)
  const _Float16* pB = wt
      + ((size_t)(nb * 8 + wc * 4 + (l31 >> 4)) * 32) * 512
      + lhi * 128 + (l31 & 15) * 8;

  floatx16 acc[2][2];
#pragma unroll
  for (int i = 0; i < 2; i++)
#pragma unroll
    for (int j = 0; j < 2; j++) acc[i][j] = (floatx16)0.0f;

  auto stageA = [&](int buf, int kt) {
#pragma unroll
    for (int s = 0; s < 2; s++) {
      const int c = wv * 2 + s;                     // rowblk 0..7
      const _Float16* g = xt + ((size_t)((mb * 8 + c) * 32 + kt)) * 512 + lane * 8;
      __builtin_amdgcn_global_load_lds(
          (const __attribute__((address_space(1))) void*)g,
          (__attribute__((address_space(3))) void*)&As[buf][c][0], 16, 0, 0);
    }
  };
  // bf[s*2+tn]: tn -> +2 groups = +4096 half8; s -> +256 halfs = +32 half8
  auto loadB = [&](int kt, half8* bf) {
    const half8* p = (const half8*)(pB + (size_t)kt * 512);
    bf[0] = p[0];
    bf[1] = p[4096];
    bf[2] = p[32];
    bf[3] = p[4128];
  };

  half8 bfc[4], bfn[4];
  stageA(0, 0);
  loadB(0, bfc);
  int buf = 0;
  for (int kt = 0; kt < 32; kt++) {
    __syncthreads();
    if (kt + 1 < 32) { stageA(buf ^ 1, kt + 1); loadB(kt + 1, bfn); }
#pragma unroll
    for (int s = 0; s < 2; s++) {        // two k16 steps
      const int kb = s * 2 + lhi;
      half8 af[2];
#pragma unroll
      for (int tm = 0; tm < 2; tm++) {
        const int cb = wr * 4 + tm * 2 + (l31 >> 4);   // rowblk
        af[tm] = *(const half8*)&As[buf][cb][kb * 128 + (l31 & 15) * 8];
      }
#pragma unroll
      for (int tm = 0; tm < 2; tm++)
#pragma unroll
        for (int tn = 0; tn < 2; tn++)
          acc[tm][tn] = __builtin_amdgcn_mfma_f32_32x32x16_f16(
              af[tm], bfc[s * 2 + tn], acc[tm][tn], 0, 0, 0);
    }
#pragma unroll
    for (int q = 0; q < 4; q++) bfc[q] = bfn[q];
    buf ^= 1;
  }

  // ---- fused epilogue: sigmoid -> gather 4 fan-in values -> LUT contraction
  // C/D 32x32: col=lane&31, row=(reg&3)+8*(reg>>2)+4*(lane>>5).
#pragma unroll
  for (int tn = 0; tn < 2; tn++) {
    const int o = (nb * 128 + wc * 64 + tn * 32 + l31) >> 2;
    const float4* lt4 = (const float4*)(lut + (size_t)o * 16);
    const float4 L0 = lt4[0], L1 = lt4[1], L2 = lt4[2], L3 = lt4[3];
#pragma unroll
    for (int tm = 0; tm < 2; tm++) {
#pragma unroll
      for (int r = 0; r < 16; r++) {
        const float v  = acc[tm][tn][r];
        const float sv = 1.0f / (1.0f + __expf(-v));
        const float s1 = __shfl_down(sv, 1);
        const float s2 = __shfl_down(sv, 2);
        const float s3 = __shfl_down(sv, 3);
        if ((lane & 3) == 0) {
          const float s0 = sv;
          const float a0 = L0.x + (L2.x - L0.x) * s3;
          const float a1 = L0.y + (L2.y - L0.y) * s3;
          const float a2 = L0.z + (L2.z - L0.z) * s3;
          const float a3 = L0.w + (L2.w - L0.w) * s3;
          const float a4 = L1.x + (L3.x - L1.x) * s3;
          const float a5 = L1.y + (L3.y - L1.y) * s3;
          const float a6 = L1.z + (L3.z - L1.z) * s3;
          const float a7 = L1.w + (L3.w - L1.w) * s3;
          const float b0 = a0 + (a4 - a0) * s2;
          const float b1 = a1 + (a5 - a1) * s2;
          const float b2 = a2 + (a6 - a2) * s2;
          const float b3 = a3 + (a7 - a3) * s2;
          const float c0 = b0 + (b2 - b0) * s1;
          const float c1 = b1 + (b3 - b1) * s1;
          const float res = c0 + (c1 - c0) * s0;
          const int row = mb * 128 + wr * 64 + tm * 32
                        + (r & 3) + 8 * (r >> 2) + 4 * lhi;
          out[(size_t)row * O_DIM + o] = res;
        }
      }
    }
  }
}

// ---------------------------------------------------------------------------
extern "C" void kernel_launch(void* const* d_in, const int* in_sizes, int n_in,
                              void* d_out, int out_size, void* d_ws, size_t ws_size,
                              hipStream_t stream) {
  const float* x      = (const float*)d_in[0];  // (B, I)
  const float* logits = (const float*)d_in[1];  // (O, N, I)
  const float* lut    = (const float*)d_in[2];  // (O, 16)
  float* out          = (float*)d_out;          // (B, O)

  _Float16* wt = (_Float16*)d_ws;                                  // 8 MB tiled
  _Float16* xt = (_Float16*)d_ws + (size_t)ON_DIM * I_DIM;         // 8 MB tiled
  // stats scratch parked in d_out (32 KB); GEMM fully overwrites d_out later.
  float2* stats = (float2*)d_out;

  ltn_prep1<<<1280, 256, 0, stream>>>(logits, x, stats, xt);
  ltn_prep2<<<256, 256, 0, stream>>>(logits, stats, wt);
  dim3 grid(32, 32);
  ltn_gemm_lut<<<grid, 256, 0, stream>>>(xt, wt, lut, out);
}